// Round 16
// baseline (213.006 us; speedup 1.0000x reference)
//
#include <hip/hip_runtime.h>
#include <hip/hip_bf16.h>
#include <math.h>

// Problem constants
#define BB 256
#define KK 32
#define DD 128
#define HH 256
#define NN 16
// d_out layout (fp32, concatenated in return order)
#define O0 ((size_t)0)
#define O1 ((size_t)33554432)
#define O2 ((size_t)37748736)
#define O3 ((size_t)71303168)

typedef float f32x4 __attribute__((ext_vector_type(4)));
typedef short s16x8 __attribute__((ext_vector_type(8)));

static __device__ __forceinline__ short f2bf(float x) {
  __hip_bfloat16 h = __float2bfloat16(x);
  return *reinterpret_cast<short*>(&h);
}
static __device__ __forceinline__ float bf2f(short s) {
  __hip_bfloat16 h;
  *reinterpret_cast<short*>(&h) = s;
  return __bfloat162float(h);
}
// pack 2 f32 -> 2 bf16 (RNE): lo16=bf16(a), hi16=bf16(b)
static __device__ __forceinline__ unsigned cvt_pk_bf16(float a, float b) {
  unsigned r;
  asm volatile("v_cvt_pk_bf16_f32 %0, %1, %2" : "=v"(r) : "v"(a), "v"(b));
  return r;
}

// exact-erf gelu via Abramowitz-Stegun 7.1.26 (|erf err| <= 1.5e-7)
static __device__ __forceinline__ float gelu_exact(float x) {
  float ax = fabsf(x) * 0.70710678118654752f;
  float t = __builtin_amdgcn_rcpf(fmaf(0.3275911f, ax, 1.0f));
  float p = fmaf(1.061405429f, t, -1.453152027f);
  p = fmaf(p, t, 1.421413741f);
  p = fmaf(p, t, -0.284496736f);
  p = fmaf(p, t, 0.254829592f);
  p *= t;
  float e = __expf(-ax * ax);
  float er = fmaf(-p, e, 1.0f);  // erf(|x|/sqrt2)
  er = copysignf(er, x);
  return 0.5f * x * (1.0f + er);
}

// ---------------------------------------------------------------------------
// Prep: z->bf16; W1 -> transposed hi/lo bf16 [512][128]; W2 -> transposed
// hi/lo [128][256]; cbT bf16 [128][32] (n>=16 zero);
// W2cb = W2@cb^T -> hi/lo bf16 [16][256]; b2cb[n] = b2 . cb[n] (fp32).
// ---------------------------------------------------------------------------
__global__ __launch_bounds__(256) void prep_kernel(
    const float* __restrict__ z, const float* __restrict__ W1,
    const float* __restrict__ W2, const float* __restrict__ cb,
    const float* __restrict__ b2,
    short* __restrict__ zb, short* __restrict__ W1th, short* __restrict__ W1tl,
    short* __restrict__ Wh, short* __restrict__ Wl, short* __restrict__ cbT,
    short* __restrict__ Vh, short* __restrict__ Vl, float* __restrict__ b2cb) {
  const int idx = blockIdx.x * 256 + threadIdx.x;  // 1,048,576 total
  zb[idx] = f2bf(z[idx]);
  if (idx < 512 * 128) {  // W1t
    int c = idx >> 7, k = idx & 127;
    float w = (c < 256) ? W1[(size_t)k * 256 + c]
                        : W1[(size_t)(128 + k) * 256 + (c - 256)];
    short h = f2bf(w);
    W1th[idx] = h;
    W1tl[idx] = f2bf(w - bf2f(h));
  }
  if (idx < 128 * 256) {  // W2t: [c][k]
    int c = idx >> 8, k = idx & 255;
    float w = W2[(size_t)k * 128 + c];
    short h = f2bf(w);
    Wh[idx] = h;
    Wl[idx] = f2bf(w - bf2f(h));
  }
  if (idx < 128 * 32) {  // cbT [c][n], zero-padded n>=16
    int c = idx >> 5, n = idx & 31;
    cbT[idx] = (n < 16) ? f2bf(cb[(size_t)n * 128 + c]) : (short)0;
  }
  if (idx < 16 * 256) {  // W2cb [n][k] = sum_c W2[k][c]*cb[n][c]
    int n = idx >> 8, k = idx & 255;
    float s = 0.f;
#pragma unroll 4
    for (int c = 0; c < 128; ++c)
      s += W2[(size_t)k * 128 + c] * cb[(size_t)n * 128 + c];
    short h = f2bf(s);
    Vh[idx] = h;
    Vl[idx] = f2bf(s - bf2f(h));
  }
  if (idx < 16) {
    float s = 0.f;
    for (int c = 0; c < 128; ++c) s += b2[c] * cb[(size_t)idx * 128 + c];
    b2cb[idx] = s;
  }
}

// ---------------------------------------------------------------------------
// H projection via MFMA: Hcat[8192][512] = zb @ W1t^T (split-bf16), b1 folded.
// ---------------------------------------------------------------------------
__global__ __launch_bounds__(256) void hproj_mfma(
    const short* __restrict__ zb, const short* __restrict__ W1th,
    const short* __restrict__ W1tl, const float* __restrict__ b1,
    float* __restrict__ H) {
  const int tid = threadIdx.x;
  const int lane = tid & 63;
  const int wv = tid >> 6;
  const int l4 = lane >> 4, l15 = lane & 15;
  const int row0 = blockIdx.x * 32;
  const int col0 = blockIdx.y * 128 + wv * 32;

  f32x4 acc[2][2];
#pragma unroll
  for (int mt = 0; mt < 2; ++mt)
#pragma unroll
    for (int nt = 0; nt < 2; ++nt)
      acc[mt][nt] = (f32x4){0.f, 0.f, 0.f, 0.f};

#pragma unroll
  for (int ks = 0; ks < 4; ++ks) {
    const int kof = ks * 32 + l4 * 8;
    s16x8 a0 = *(const s16x8*)(zb + (size_t)(row0 + l15) * 128 + kof);
    s16x8 a1 = *(const s16x8*)(zb + (size_t)(row0 + 16 + l15) * 128 + kof);
    s16x8 bh0 = *(const s16x8*)(W1th + (size_t)(col0 + l15) * 128 + kof);
    s16x8 bh1 = *(const s16x8*)(W1th + (size_t)(col0 + 16 + l15) * 128 + kof);
    s16x8 bl0 = *(const s16x8*)(W1tl + (size_t)(col0 + l15) * 128 + kof);
    s16x8 bl1 = *(const s16x8*)(W1tl + (size_t)(col0 + 16 + l15) * 128 + kof);
    acc[0][0] = __builtin_amdgcn_mfma_f32_16x16x32_bf16(a0, bh0, acc[0][0], 0, 0, 0);
    acc[0][0] = __builtin_amdgcn_mfma_f32_16x16x32_bf16(a0, bl0, acc[0][0], 0, 0, 0);
    acc[0][1] = __builtin_amdgcn_mfma_f32_16x16x32_bf16(a0, bh1, acc[0][1], 0, 0, 0);
    acc[0][1] = __builtin_amdgcn_mfma_f32_16x16x32_bf16(a0, bl1, acc[0][1], 0, 0, 0);
    acc[1][0] = __builtin_amdgcn_mfma_f32_16x16x32_bf16(a1, bh0, acc[1][0], 0, 0, 0);
    acc[1][0] = __builtin_amdgcn_mfma_f32_16x16x32_bf16(a1, bl0, acc[1][0], 0, 0, 0);
    acc[1][1] = __builtin_amdgcn_mfma_f32_16x16x32_bf16(a1, bh1, acc[1][1], 0, 0, 0);
    acc[1][1] = __builtin_amdgcn_mfma_f32_16x16x32_bf16(a1, bl1, acc[1][1], 0, 0, 0);
  }

#pragma unroll
  for (int nt = 0; nt < 2; ++nt) {
    const int col = col0 + nt * 16 + l15;
    const float bias = (col0 < 256) ? b1[col] : 0.f;  // wave-uniform branch
#pragma unroll
    for (int mt = 0; mt < 2; ++mt)
#pragma unroll
      for (int r = 0; r < 4; ++r)
        H[(size_t)(row0 + mt * 16 + l4 * 4 + r) * 512 + col] =
            acc[mt][nt][r] + bias;
  }
}

#define MFMA16(d, a, bsrc) d = __builtin_amdgcn_mfma_f32_16x16x32_bf16(a, bsrc, d, 0, 0, 0)

// ---------------------------------------------------------------------------
// Kernel B: one block (4 waves) per (b,i). Single-bf16 A, split W2.
// TWO barriers; no e-LDS round trip (logits via V = W2@cb^T, K=256).
//  A:  gelu(Hi+Hj) -> bf16 in swizzled LDS (16 KB; stays live through L)
//  G:  swapped e-GEMM, 2-pass (Wh+Wl)xAh = 8 MFMA/ks
//  E:  e fp32 -> global float4 straight from accumulators (pure stores)
//  L:  logits = Ah @ (Vh+Vl), K=256, 2 MFMA/ks (waves 0,1); softmax in-reg
//  M:  m^T = cbT x alpha^T swapped MFMA -> float4 stores
// LDS 18 KB, VGPR ~32 -> 8 blocks/CU (launch_bounds(256,8)).
// XCD swizzle: same-b blocks share an XCD (Hj L2 reuse).
// ---------------------------------------------------------------------------
__global__ __launch_bounds__(256, 8) void pair_kernel(
    const float* __restrict__ Hcat, const short* __restrict__ Wh,
    const short* __restrict__ Wl, const float* __restrict__ b2,
    const short* __restrict__ Vh, const short* __restrict__ Vl,
    const float* __restrict__ b2cb, const short* __restrict__ cbT,
    float* __restrict__ out) {
  __shared__ short sAh[32 * 256];  // 16 KB gelu bf16, XOR-swizzled
  __shared__ short sAlp[32 * 32];  // 2 KB alpha bf16, n zero-padded to 32

  const int tid = threadIdx.x;
  // bijective XCD swizzle (8192 % 8 == 0): same-b blocks share an XCD
  const int dd = blockIdx.x;
  const int blk = (dd & 7) * 1024 + (dd >> 3);  // = b*K + i
  const int b = blk >> 5;

  // ---- Phase A: gelu -> bf16 into swizzled LDS (b1 pre-folded) ----
  {
    const int k0 = (tid & 127) * 2;
    const int pb = (tid >> 7) * 16;
    const float2 hiv = *(const float2*)(Hcat + (size_t)blk * 512 + k0);
    const float hx = hiv.x;
    const float hy = hiv.y;
    const float* hjp = Hcat + ((size_t)b * KK + pb) * 512 + 256 + k0;
    unsigned* aH = (unsigned*)sAh;
    const int cw = tid & 127;
    // zero-init alpha buffer (needed before Phase L, not before A)
    ((unsigned*)sAlp)[tid] = 0u;
    ((unsigned*)sAlp)[tid + 256] = 0u;
#pragma unroll 4
    for (int p = 0; p < 16; ++p) {
      const int row = pb + p;
      float2 hj = *(const float2*)(hjp + (size_t)p * 512);
      float g0 = gelu_exact(hx + hj.x);
      float g1 = gelu_exact(hy + hj.y);
      const int wi = row * 128 + ((cw ^ ((row & 7) << 2)));
      aH[wi] = cvt_pk_bf16(g0, g1);
    }
  }
  __syncthreads();  // barrier 1

  // ---- Phase G: swapped e-GEMM, 2-pass split-W (8 MFMA/ks) ----
  const int lane = tid & 63;
  const int wv = tid >> 6;  // wave owns e-cols nb..nb+31
  const int nb = wv * 32;
  const int l4 = lane >> 4;
  const int l15 = lane & 15;

  // eacc[w][a]: lane holds e[row = a*16 + l15][cols = nb + w*16 + l4*4 .. +3]
  f32x4 eacc[2][2];
#pragma unroll
  for (int w = 0; w < 2; ++w)
#pragma unroll
    for (int a = 0; a < 2; ++a)
      eacc[w][a] = (f32x4){0.f, 0.f, 0.f, 0.f};

  const int sw = (l15 & 7) << 4;
  const char* pAh = (const char*)sAh;
  const size_t gB0 = (size_t)(nb + l15) * 256 + l4 * 8;

#pragma unroll
  for (int ks = 0; ks < 8; ++ks) {
    const int cbyte = ks * 64 + l4 * 16;
    const int o0 = l15 * 512 + (cbyte ^ sw);
    const int o1 = (16 + l15) * 512 + (cbyte ^ sw);
    s16x8 ah0 = *(const s16x8*)(pAh + o0);
    s16x8 ah1 = *(const s16x8*)(pAh + o1);
    const size_t g0 = gB0 + ks * 32;
    const size_t g1 = g0 + 16 * 256;
    s16x8 bh0 = *(const s16x8*)(Wh + g0);
    s16x8 bh1 = *(const s16x8*)(Wh + g1);
    s16x8 bl0 = *(const s16x8*)(Wl + g0);
    s16x8 bl1 = *(const s16x8*)(Wl + g1);

    // e^T = (Wh + Wl)^T Ah^T
    MFMA16(eacc[0][0], bh0, ah0); MFMA16(eacc[0][0], bl0, ah0);
    MFMA16(eacc[0][1], bh0, ah1); MFMA16(eacc[0][1], bl0, ah1);
    MFMA16(eacc[1][0], bh1, ah0); MFMA16(eacc[1][0], bl1, ah0);
    MFMA16(eacc[1][1], bh1, ah1); MFMA16(eacc[1][1], bl1, ah1);
  }

  // ---- Phase E: +b2, e -> global float4 (pure stores, no LDS) ----
  {
    const float4 b2q0 = *(const float4*)(b2 + nb + l4 * 4);
    const float4 b2q1 = *(const float4*)(b2 + nb + 16 + l4 * 4);
    float* eg = out + O2 + (size_t)blk * (KK * DD);
#pragma unroll
    for (int a = 0; a < 2; ++a) {
      const int row = a * 16 + l15;
      float4 v0 = make_float4(eacc[0][a][0] + b2q0.x, eacc[0][a][1] + b2q0.y,
                              eacc[0][a][2] + b2q0.z, eacc[0][a][3] + b2q0.w);
      float4 v1 = make_float4(eacc[1][a][0] + b2q1.x, eacc[1][a][1] + b2q1.y,
                              eacc[1][a][2] + b2q1.z, eacc[1][a][3] + b2q1.w);
      *(float4*)(eg + row * 128 + nb + l4 * 4) = v0;
      *(float4*)(eg + row * 128 + nb + 16 + l4 * 4) = v1;
    }
  }

  // ---- Phase L: logits = Ah @ V, K=256, waves 0,1 (Ah still live in LDS) ----
  if (wv < 2) {
    f32x4 lacc = (f32x4){0.f, 0.f, 0.f, 0.f};
    const int rowa = wv * 16 + l15;      // (rowa & 7) == (l15 & 7) -> same sw
    const int obase = rowa * 512;
    const size_t gV0 = (size_t)l15 * 256 + l4 * 8;
#pragma unroll
    for (int ks = 0; ks < 8; ++ks) {
      const int cbyte = ks * 64 + l4 * 16;
      const int o = obase + (cbyte ^ sw);
      s16x8 ah = *(const s16x8*)(pAh + o);
      s16x8 vh = *(const s16x8*)(Vh + gV0 + ks * 32);
      s16x8 vl = *(const s16x8*)(Vl + gV0 + ks * 32);
      MFMA16(lacc, ah, vh);
      MFMA16(lacc, ah, vl);
    }
    const float bcv = b2cb[l15];
    float* lg_out = out + O3 + (size_t)blk * (KK * NN);
    float* ag_out = out + O1 + (size_t)blk * (KK * NN);
#pragma unroll
    for (int r = 0; r < 4; ++r) {
      const int row = wv * 16 + l4 * 4 + r;
      float lg = (lacc[r] + bcv) * 10.0f;
      float mx = lg;
#pragma unroll
      for (int m = 1; m < 16; m <<= 1) mx = fmaxf(mx, __shfl_xor(mx, m));
      float p = __expf(lg - mx);
      float s = p;
#pragma unroll
      for (int m = 1; m < 16; m <<= 1) s += __shfl_xor(s, m);
      float a = p / s;
      lg_out[row * 16 + l15] = lg;
      ag_out[row * 16 + l15] = a;
      sAlp[row * 32 + l15] = f2bf(a);
    }
  }
  __syncthreads();  // barrier 2

  // ---- Phase M: m^T = cbT x alpha^T (swapped), float4 stores ----
  {
#pragma unroll
    for (int jt = 0; jt < 2; ++jt) {
      s16x8 af = *(const s16x8*)(sAlp + (jt * 16 + l15) * 32 + l4 * 8);
      float* mg = out + O0 + (size_t)blk * (KK * DD) + (size_t)(jt * 16 + l15) * DD;
#pragma unroll
      for (int cp = 0; cp < 2; ++cp) {
        const int cc = wv + cp * 4;
        s16x8 cf = *(const s16x8*)(cbT + (size_t)(cc * 16 + l15) * 32 + l4 * 8);
        f32x4 mac = (f32x4){0.f, 0.f, 0.f, 0.f};
        MFMA16(mac, cf, af);  // lane: m[j = jt*16+l15][c = cc*16 + l4*4 + r]
        *(float4*)(mg + cc * 16 + l4 * 4) = *(float4*)&mac;
      }
    }
  }
}

extern "C" void kernel_launch(void* const* d_in, const int* in_sizes, int n_in,
                              void* d_out, int out_size, void* d_ws, size_t ws_size,
                              hipStream_t stream) {
  const float* z  = (const float*)d_in[0];   // (256,32,128)
  const float* W1 = (const float*)d_in[1];   // (256,256)
  const float* b1 = (const float*)d_in[2];   // (256,)
  const float* W2 = (const float*)d_in[3];   // (256,128)
  const float* b2 = (const float*)d_in[4];   // (128,)
  const float* cb = (const float*)d_in[5];   // (16,128)
  float* out = (float*)d_out;

  // ws: Hcat fp32 [8192][512] | zb | W1th | W1tl | Wh | Wl | cbT | Vh | Vl | b2cb
  float* Hcat = (float*)d_ws;
  short* zb   = (short*)(Hcat + (size_t)8192 * 512);
  short* W1th = zb + (size_t)1048576;
  short* W1tl = W1th + (size_t)65536;
  short* Wh   = W1tl + (size_t)65536;
  short* Wl   = Wh + (size_t)32768;
  short* cbT  = Wl + (size_t)32768;
  short* Vh   = cbT + (size_t)4096;
  short* Vl   = Vh + (size_t)4096;
  float* b2cb = (float*)(Vl + (size_t)4096);

  prep_kernel<<<4096, 256, 0, stream>>>(z, W1, W2, cb, b2, zb, W1th, W1tl, Wh,
                                        Wl, cbT, Vh, Vl, b2cb);
  hproj_mfma<<<dim3(256, 4), 256, 0, stream>>>(zb, W1th, W1tl, b1, Hcat);
  pair_kernel<<<BB * KK, 256, 0, stream>>>(Hcat, Wh, Wl, b2, Vh, Vl, b2cb,
                                           cbT, out);
}

// Round 17
// 195.834 us; speedup vs baseline: 1.0877x; 1.0877x over previous
//
#include <hip/hip_runtime.h>
#include <hip/hip_bf16.h>
#include <math.h>

// Problem constants
#define BB 256
#define KK 32
#define DD 128
#define HH 256
#define NN 16
// d_out layout (fp32, concatenated in return order)
#define O0 ((size_t)0)
#define O1 ((size_t)33554432)
#define O2 ((size_t)37748736)
#define O3 ((size_t)71303168)

typedef float f32x4 __attribute__((ext_vector_type(4)));
typedef short s16x8 __attribute__((ext_vector_type(8)));

static __device__ __forceinline__ short f2bf(float x) {
  __hip_bfloat16 h = __float2bfloat16(x);
  return *reinterpret_cast<short*>(&h);
}
static __device__ __forceinline__ float bf2f(short s) {
  __hip_bfloat16 h;
  *reinterpret_cast<short*>(&h) = s;
  return __bfloat162float(h);
}
// pack 2 f32 -> 2 bf16 (RNE): lo16=bf16(a), hi16=bf16(b)
static __device__ __forceinline__ unsigned cvt_pk_bf16(float a, float b) {
  unsigned r;
  asm volatile("v_cvt_pk_bf16_f32 %0, %1, %2" : "=v"(r) : "v"(a), "v"(b));
  return r;
}

// exact-erf gelu via Abramowitz-Stegun 7.1.26 (|erf err| <= 1.5e-7)
static __device__ __forceinline__ float gelu_exact(float x) {
  float ax = fabsf(x) * 0.70710678118654752f;
  float t = __builtin_amdgcn_rcpf(fmaf(0.3275911f, ax, 1.0f));
  float p = fmaf(1.061405429f, t, -1.453152027f);
  p = fmaf(p, t, 1.421413741f);
  p = fmaf(p, t, -0.284496736f);
  p = fmaf(p, t, 0.254829592f);
  p *= t;
  float e = __expf(-ax * ax);
  float er = fmaf(-p, e, 1.0f);  // erf(|x|/sqrt2)
  er = copysignf(er, x);
  return 0.5f * x * (1.0f + er);
}

// ---------------------------------------------------------------------------
// Prep: z -> bf16; W1 -> transposed hi/lo bf16 [512][128];
//       W2 -> transposed hi/lo bf16 [128][256]; cb -> hi/lo [n][k];
//       cbT -> bf16 [c 128][n 32] (n>=16 zero, for Phase M MFMA).
// ---------------------------------------------------------------------------
__global__ __launch_bounds__(256) void prep_kernel(
    const float* __restrict__ z, const float* __restrict__ W1,
    const float* __restrict__ W2, const float* __restrict__ cb,
    short* __restrict__ zb, short* __restrict__ W1th, short* __restrict__ W1tl,
    short* __restrict__ Wh, short* __restrict__ Wl,
    short* __restrict__ cbh, short* __restrict__ cbl, short* __restrict__ cbT) {
  const int idx = blockIdx.x * 256 + threadIdx.x;  // 1,048,576 total
  zb[idx] = f2bf(z[idx]);
  if (idx < 512 * 128) {  // W1t
    int c = idx >> 7, k = idx & 127;
    float w = (c < 256) ? W1[(size_t)k * 256 + c]
                        : W1[(size_t)(128 + k) * 256 + (c - 256)];
    short h = f2bf(w);
    W1th[idx] = h;
    W1tl[idx] = f2bf(w - bf2f(h));
  }
  if (idx < 128 * 256) {  // W2t: [c][k]
    int c = idx >> 8, k = idx & 255;
    float w = W2[(size_t)k * 128 + c];
    short h = f2bf(w);
    Wh[idx] = h;
    Wl[idx] = f2bf(w - bf2f(h));
  }
  if (idx < 2048) {  // cb [n][k] splits
    float v = cb[idx];
    short h = f2bf(v);
    cbh[idx] = h;
    cbl[idx] = f2bf(v - bf2f(h));
  }
  if (idx < 128 * 32) {  // cbT [c][n], zero-padded n>=16
    int c = idx >> 5, n = idx & 31;
    cbT[idx] = (n < 16) ? f2bf(cb[(size_t)n * 128 + c]) : (short)0;
  }
}

// ---------------------------------------------------------------------------
// H projection via MFMA: Hcat[8192][512] = zb @ W1t^T (split-bf16), b1 folded.
// ---------------------------------------------------------------------------
__global__ __launch_bounds__(256) void hproj_mfma(
    const short* __restrict__ zb, const short* __restrict__ W1th,
    const short* __restrict__ W1tl, const float* __restrict__ b1,
    float* __restrict__ H) {
  const int tid = threadIdx.x;
  const int lane = tid & 63;
  const int wv = tid >> 6;
  const int l4 = lane >> 4, l15 = lane & 15;
  const int row0 = blockIdx.x * 32;
  const int col0 = blockIdx.y * 128 + wv * 32;

  f32x4 acc[2][2];
#pragma unroll
  for (int mt = 0; mt < 2; ++mt)
#pragma unroll
    for (int nt = 0; nt < 2; ++nt)
      acc[mt][nt] = (f32x4){0.f, 0.f, 0.f, 0.f};

#pragma unroll
  for (int ks = 0; ks < 4; ++ks) {
    const int kof = ks * 32 + l4 * 8;
    s16x8 a0 = *(const s16x8*)(zb + (size_t)(row0 + l15) * 128 + kof);
    s16x8 a1 = *(const s16x8*)(zb + (size_t)(row0 + 16 + l15) * 128 + kof);
    s16x8 bh0 = *(const s16x8*)(W1th + (size_t)(col0 + l15) * 128 + kof);
    s16x8 bh1 = *(const s16x8*)(W1th + (size_t)(col0 + 16 + l15) * 128 + kof);
    s16x8 bl0 = *(const s16x8*)(W1tl + (size_t)(col0 + l15) * 128 + kof);
    s16x8 bl1 = *(const s16x8*)(W1tl + (size_t)(col0 + 16 + l15) * 128 + kof);
    acc[0][0] = __builtin_amdgcn_mfma_f32_16x16x32_bf16(a0, bh0, acc[0][0], 0, 0, 0);
    acc[0][0] = __builtin_amdgcn_mfma_f32_16x16x32_bf16(a0, bl0, acc[0][0], 0, 0, 0);
    acc[0][1] = __builtin_amdgcn_mfma_f32_16x16x32_bf16(a0, bh1, acc[0][1], 0, 0, 0);
    acc[0][1] = __builtin_amdgcn_mfma_f32_16x16x32_bf16(a0, bl1, acc[0][1], 0, 0, 0);
    acc[1][0] = __builtin_amdgcn_mfma_f32_16x16x32_bf16(a1, bh0, acc[1][0], 0, 0, 0);
    acc[1][0] = __builtin_amdgcn_mfma_f32_16x16x32_bf16(a1, bl0, acc[1][0], 0, 0, 0);
    acc[1][1] = __builtin_amdgcn_mfma_f32_16x16x32_bf16(a1, bh1, acc[1][1], 0, 0, 0);
    acc[1][1] = __builtin_amdgcn_mfma_f32_16x16x32_bf16(a1, bl1, acc[1][1], 0, 0, 0);
  }

#pragma unroll
  for (int nt = 0; nt < 2; ++nt) {
    const int col = col0 + nt * 16 + l15;
    const float bias = (col0 < 256) ? b1[col] : 0.f;  // wave-uniform branch
#pragma unroll
    for (int mt = 0; mt < 2; ++mt)
#pragma unroll
      for (int r = 0; r < 4; ++r)
        H[(size_t)(row0 + mt * 16 + l4 * 4 + r) * 512 + col] =
            acc[mt][nt][r] + bias;
  }
}

#define MFMA16(d, a, bsrc) d = __builtin_amdgcn_mfma_f32_16x16x32_bf16(a, bsrc, d, 0, 0, 0)

// ---------------------------------------------------------------------------
// Kernel B: one block (4 waves) per (b,i). Single-bf16 A, split W2.
//  A:  gelu(Hi+Hj) -> bf16 in swizzled LDS (16 KB)
//  G:  swapped e-GEMM, 2-pass (Wh+Wl)xAh = 8 MFMA/ks
//  E:  e fp32 -> global float4; e hi/lo splits -> LDS (overlays dead Ah)
//  L:  logits = e @ cb^T via 3-pass MFMA K=128 (waves 0,1), softmax in-reg
//  M:  m^T = cbT x alpha^T swapped MFMA -> float4 stores
// LDS 18.4 KB, VGPR ~40 -> EIGHT blocks/CU (launch_bounds(256,8), cap 64,
// measured usage 40 so no allocator squeeze; 8x18.4=147KB < 160KB).
// XCD swizzle: same-b blocks share an XCD (Hj L2 reuse).
// ---------------------------------------------------------------------------
__global__ __launch_bounds__(256, 8) void pair_kernel(
    const float* __restrict__ Hcat, const short* __restrict__ Wh,
    const short* __restrict__ Wl, const float* __restrict__ b2,
    const short* __restrict__ cbh, const short* __restrict__ cbl,
    const short* __restrict__ cbT, float* __restrict__ out) {
  __shared__ union {
    short Ah[32 * 256];  // 16 KB gelu bf16, XOR-swizzled (dead after G)
    struct { short Eh[32 * 128]; short El[32 * 128]; } e;  // e splits, swizzled
  } u;
  __shared__ short sAlp[32 * 32];  // 2 KB alpha bf16, n zero-padded to 32

  const int tid = threadIdx.x;
  // bijective XCD swizzle (8192 % 8 == 0): same-b blocks share an XCD
  const int dd = blockIdx.x;
  const int blk = (dd & 7) * 1024 + (dd >> 3);  // = b*K + i
  const int b = blk >> 5;

  // ---- Phase A: gelu -> bf16 into swizzled LDS (b1 pre-folded) ----
  {
    const int k0 = (tid & 127) * 2;
    const int pb = (tid >> 7) * 16;
    const float2 hiv = *(const float2*)(Hcat + (size_t)blk * 512 + k0);
    const float hx = hiv.x;
    const float hy = hiv.y;
    const float* hjp = Hcat + ((size_t)b * KK + pb) * 512 + 256 + k0;
    unsigned* aH = (unsigned*)u.Ah;
    const int cw = tid & 127;
    // zero-init alpha buffer (needed before Phase L, not before A)
    ((unsigned*)sAlp)[tid] = 0u;
    ((unsigned*)sAlp)[tid + 256] = 0u;
#pragma unroll 4
    for (int p = 0; p < 16; ++p) {
      const int row = pb + p;
      float2 hj = *(const float2*)(hjp + (size_t)p * 512);
      float g0 = gelu_exact(hx + hj.x);
      float g1 = gelu_exact(hy + hj.y);
      const int wi = row * 128 + ((cw ^ ((row & 7) << 2)));
      aH[wi] = cvt_pk_bf16(g0, g1);
    }
  }
  __syncthreads();  // barrier 1

  // ---- Phase G: swapped e-GEMM, 2-pass split-W (8 MFMA/ks) ----
  const int lane = tid & 63;
  const int wv = tid >> 6;  // wave owns e-cols nb..nb+31
  const int nb = wv * 32;
  const int l4 = lane >> 4;
  const int l15 = lane & 15;

  // eacc[w][a]: lane holds e[row = a*16 + l15][cols = nb + w*16 + l4*4 .. +3]
  f32x4 eacc[2][2];
#pragma unroll
  for (int w = 0; w < 2; ++w)
#pragma unroll
    for (int a = 0; a < 2; ++a)
      eacc[w][a] = (f32x4){0.f, 0.f, 0.f, 0.f};

  const int sw = (l15 & 7) << 4;
  const char* pAh = (const char*)u.Ah;
  const size_t gB0 = (size_t)(nb + l15) * 256 + l4 * 8;

#pragma unroll
  for (int ks = 0; ks < 8; ++ks) {
    const int cbyte = ks * 64 + l4 * 16;
    const int o0 = l15 * 512 + (cbyte ^ sw);
    const int o1 = (16 + l15) * 512 + (cbyte ^ sw);
    s16x8 ah0 = *(const s16x8*)(pAh + o0);
    s16x8 ah1 = *(const s16x8*)(pAh + o1);
    const size_t g0 = gB0 + ks * 32;
    const size_t g1 = g0 + 16 * 256;
    s16x8 bh0 = *(const s16x8*)(Wh + g0);
    s16x8 bh1 = *(const s16x8*)(Wh + g1);
    s16x8 bl0 = *(const s16x8*)(Wl + g0);
    s16x8 bl1 = *(const s16x8*)(Wl + g1);

    // e^T = (Wh + Wl)^T Ah^T
    MFMA16(eacc[0][0], bh0, ah0); MFMA16(eacc[0][0], bl0, ah0);
    MFMA16(eacc[0][1], bh0, ah1); MFMA16(eacc[0][1], bl0, ah1);
    MFMA16(eacc[1][0], bh1, ah0); MFMA16(eacc[1][0], bl1, ah0);
    MFMA16(eacc[1][1], bh1, ah1); MFMA16(eacc[1][1], bl1, ah1);
  }

  __syncthreads();  // barrier 2: Ah consumed by all waves; u.e may be written

  // ---- Phase E: +b2, float4 e to global; split bf16 -> LDS (b64 writes) ----
  {
    const float4 b2q0 = *(const float4*)(b2 + nb + l4 * 4);
    const float4 b2q1 = *(const float4*)(b2 + nb + 16 + l4 * 4);
    float* eg = out + O2 + (size_t)blk * (KK * DD);
    char* pEh = (char*)u.e.Eh;
    char* pEl = (char*)u.e.El;
#pragma unroll
    for (int a = 0; a < 2; ++a) {
      const int row = a * 16 + l15;
      const int rsw = (row & 7) << 4;
#pragma unroll
      for (int w = 0; w < 2; ++w) {
        const float4 bq = w ? b2q1 : b2q0;
        float4 v = make_float4(eacc[w][a][0] + bq.x, eacc[w][a][1] + bq.y,
                               eacc[w][a][2] + bq.z, eacc[w][a][3] + bq.w);
        const int c0 = nb + w * 16 + l4 * 4;
        *(float4*)(eg + row * 128 + c0) = v;
        unsigned hp0 = cvt_pk_bf16(v.x, v.y);
        unsigned hp1 = cvt_pk_bf16(v.z, v.w);
        float f0 = __uint_as_float(hp0 << 16);
        float f1 = __uint_as_float(hp0 & 0xFFFF0000u);
        float f2 = __uint_as_float(hp1 << 16);
        float f3 = __uint_as_float(hp1 & 0xFFFF0000u);
        unsigned lp0 = cvt_pk_bf16(v.x - f0, v.y - f1);
        unsigned lp1 = cvt_pk_bf16(v.z - f2, v.w - f3);
        const int off = row * 256 + ((c0 * 2) ^ rsw);
        *(uint2*)(pEh + off) = make_uint2(hp0, hp1);
        *(uint2*)(pEl + off) = make_uint2(lp0, lp1);
      }
    }
  }
  __syncthreads();  // barrier 3

  // ---- Phase L: logits via 3-pass MFMA K=128 (waves 0,1), softmax in-reg ----
  if (wv < 2) {
    const int mrow = wv * 16;
    f32x4 lacc = (f32x4){0.f, 0.f, 0.f, 0.f};
    const char* pEh = (const char*)u.e.Eh;
    const char* pEl = (const char*)u.e.El;
    const int rowa = mrow + l15;
    const int rsw = (rowa & 7) << 4;
#pragma unroll
    for (int ks = 0; ks < 4; ++ks) {
      const int cbyte = ks * 64 + l4 * 16;
      const int o = rowa * 256 + (cbyte ^ rsw);
      s16x8 eh = *(const s16x8*)(pEh + o);
      s16x8 el = *(const s16x8*)(pEl + o);
      const size_t g = (size_t)l15 * 128 + ks * 32 + l4 * 8;
      s16x8 ch = *(const s16x8*)(cbh + g);
      s16x8 cl = *(const s16x8*)(cbl + g);
      MFMA16(lacc, eh, ch);
      MFMA16(lacc, el, ch);
      MFMA16(lacc, eh, cl);
    }
    float* lg_out = out + O3 + (size_t)blk * (KK * NN);
    float* ag_out = out + O1 + (size_t)blk * (KK * NN);
#pragma unroll
    for (int r = 0; r < 4; ++r) {
      const int row = mrow + l4 * 4 + r;
      float lg = lacc[r] * 10.0f;
      float mx = lg;
#pragma unroll
      for (int m = 1; m < 16; m <<= 1) mx = fmaxf(mx, __shfl_xor(mx, m));
      float p = __expf(lg - mx);
      float s = p;
#pragma unroll
      for (int m = 1; m < 16; m <<= 1) s += __shfl_xor(s, m);
      float a = p / s;
      lg_out[row * 16 + l15] = lg;
      ag_out[row * 16 + l15] = a;
      sAlp[row * 32 + l15] = f2bf(a);
    }
  }
  __syncthreads();  // barrier 4

  // ---- Phase M: m^T = cbT x alpha^T (swapped), float4 stores ----
  {
#pragma unroll
    for (int jt = 0; jt < 2; ++jt) {
      s16x8 af = *(const s16x8*)(sAlp + (jt * 16 + l15) * 32 + l4 * 8);
      float* mg = out + O0 + (size_t)blk * (KK * DD) + (size_t)(jt * 16 + l15) * DD;
#pragma unroll
      for (int cp = 0; cp < 2; ++cp) {
        const int cc = wv + cp * 4;
        s16x8 cf = *(const s16x8*)(cbT + (size_t)(cc * 16 + l15) * 32 + l4 * 8);
        f32x4 mac = (f32x4){0.f, 0.f, 0.f, 0.f};
        MFMA16(mac, cf, af);  // lane: m[j = jt*16+l15][c = cc*16 + l4*4 + r]
        *(float4*)(mg + cc * 16 + l4 * 4) = *(float4*)&mac;
      }
    }
  }
}

extern "C" void kernel_launch(void* const* d_in, const int* in_sizes, int n_in,
                              void* d_out, int out_size, void* d_ws, size_t ws_size,
                              hipStream_t stream) {
  const float* z  = (const float*)d_in[0];   // (256,32,128)
  const float* W1 = (const float*)d_in[1];   // (256,256)
  const float* b1 = (const float*)d_in[2];   // (256,)
  const float* W2 = (const float*)d_in[3];   // (256,128)
  const float* b2 = (const float*)d_in[4];   // (128,)
  const float* cb = (const float*)d_in[5];   // (16,128)
  float* out = (float*)d_out;

  // ws: Hcat fp32 [8192][512] | zb | W1th | W1tl | Wh | Wl | cbh | cbl | cbT
  float* Hcat = (float*)d_ws;
  short* zb   = (short*)(Hcat + (size_t)8192 * 512);
  short* W1th = zb + (size_t)1048576;
  short* W1tl = W1th + (size_t)65536;
  short* Wh   = W1tl + (size_t)65536;
  short* Wl   = Wh + (size_t)32768;
  short* cbh  = Wl + (size_t)32768;
  short* cbl  = cbh + (size_t)2048;
  short* cbT  = cbl + (size_t)2048;

  prep_kernel<<<4096, 256, 0, stream>>>(z, W1, W2, cb, zb, W1th, W1tl, Wh, Wl,
                                        cbh, cbl, cbT);
  hproj_mfma<<<dim3(256, 4), 256, 0, stream>>>(zb, W1th, W1tl, b1, Hcat);
  pair_kernel<<<BB * KK, 256, 0, stream>>>(Hcat, Wh, Wl, b2, cbh, cbl, cbT, out);
}